// Round 1
// baseline (231.103 us; speedup 1.0000x reference)
//
#include <hip/hip_runtime.h>
#include <hip/hip_bf16.h>

#define Hdim 256
#define Tdim 256
#define Bdim 512
#define TT   64
#define NTHR 512

typedef __attribute__((ext_vector_type(8))) short s16x8;
typedef __attribute__((ext_vector_type(4))) float f32x4;

__device__ __forceinline__ unsigned short f2bf_rne(float x) {
    unsigned int u = __builtin_bit_cast(unsigned int, x);
    unsigned int r = u + 0x7FFFu + ((u >> 16) & 1u);
    return (unsigned short)(r >> 16);
}
__device__ __forceinline__ float bf2f(unsigned short h) {
    unsigned int u = ((unsigned int)h) << 16;
    return __builtin_bit_cast(float, u);
}
__device__ __forceinline__ unsigned int cvt_pk_bf16(float lo, float hi) {
    unsigned int r;
    asm("v_cvt_pk_bf16_f32 %0, %1, %2" : "=v"(r) : "v"(lo), "v"(hi));
    return r;
}
__device__ __forceinline__ f32x4 mfma16(s16x8 a, s16x8 b, f32x4 c) {
    return __builtin_amdgcn_mfma_f32_16x16x32_bf16(a, b, c, 0, 0, 0);
}
__device__ __forceinline__ float fast_tanh(float z) {
    // tanh(z) = 1 - 2/(exp(2z)+1); saturates correctly at +-inf
    float e = __expf(2.0f * z);
    return 1.0f - 2.0f / (e + 1.0f);
}

// ---------------- prep: split weights into bf16 hi/lo ----------------
__global__ __launch_bounds__(256) void prep_weights(
        const float* __restrict__ W_Ih, const float* __restrict__ W_oI,
        unsigned short* __restrict__ Whi1, unsigned short* __restrict__ Wlo1,
        unsigned short* __restrict__ Whi2, unsigned short* __restrict__ Wlo2) {
    int idx = blockIdx.x * 256 + threadIdx.x;
    if (idx < Hdim * Hdim) {
        float w = W_Ih[idx];
        unsigned short hi = f2bf_rne(w);
        Whi1[idx] = hi;
        Wlo1[idx] = f2bf_rne(w - bf2f(hi));
        w = W_oI[idx];
        hi = f2bf_rne(w);
        Whi2[idx] = hi;
        Wlo2[idx] = f2bf_rne(w - bf2f(hi));
    }
}

// ---------------- prep: current projection cp[b,o] = h_hat @ W_I^T + b_I --------
__global__ __launch_bounds__(256) void cp_kernel(
        const float* __restrict__ h_tilde, const float* __restrict__ c_t,
        const float* __restrict__ W_I, const float* __restrict__ b_I,
        float* __restrict__ cp) {
    int b = blockIdx.x;
    int tid = threadIdx.x, w = tid >> 6, lane = tid & 63;
    __shared__ float hh[2 * Hdim];
    for (int i = tid; i < 2 * Hdim; i += 256)
        hh[i] = (i < Hdim) ? h_tilde[b * Hdim + i] : c_t[b * Hdim + i - Hdim];
    __syncthreads();
    for (int o = w; o < Hdim; o += 4) {
        float s = 0.f;
        const float* wr = W_I + (size_t)o * (2 * Hdim);
        #pragma unroll
        for (int k = lane; k < 2 * Hdim; k += 64) s += hh[k] * wr[k];
        #pragma unroll
        for (int d = 1; d < 64; d <<= 1) s += __shfl_xor(s, d, 64);
        if (lane == 0) cp[b * Hdim + o] = s + b_I[o];
    }
}

// ---------------- fused main kernel: one block per batch row ----------------
__global__ __launch_bounds__(NTHR, 1) void attn_main(
        const float* __restrict__ hist, const float* __restrict__ dT,
        const float* __restrict__ dL, const float* __restrict__ cp,
        const unsigned short* __restrict__ Whi1, const unsigned short* __restrict__ Wlo1,
        const unsigned short* __restrict__ Whi2, const unsigned short* __restrict__ Wlo2,
        const float* __restrict__ wI1T, const float* __restrict__ wI1L,
        const float* __restrict__ b_oI, const float* __restrict__ v_t,
        float* __restrict__ out) {
    __shared__ float histf[TT][Hdim + 4];            // 66,560 B  (fp32 hist tile)
    __shared__ unsigned short Ihi[TT][Hdim + 8];     // 33,792 B
    __shared__ unsigned short Ilo[TT][Hdim + 8];     // 33,792 B
    __shared__ float cpb[Hdim], wTl[Hdim], wLl[Hdim], bol[Hdim], vvl[Hdim];
    __shared__ float sc_part[8][TT];
    __shared__ float scores_all[Tdim];
    __shared__ float p_t[TT], dtl[TT], dll[TT];
    __shared__ float s_acc[Hdim];
    __shared__ float m_run_s, l_run_s, fac_s;

    const int b = blockIdx.x;
    const int tid = threadIdx.x;
    const int w = tid >> 6, lane = tid & 63;
    const int c = lane & 15, g = lane >> 4;
    const int ob = w * 32;                  // this wave's 32-col slice of [0,256)

    for (int i = tid; i < Hdim; i += NTHR) {
        cpb[i] = cp[b * Hdim + i];
        wTl[i] = wI1T[i];
        wLl[i] = wI1L[i];
        bol[i] = b_oI[i];
        vvl[i] = v_t[i];
        s_acc[i] = 0.f;
    }
    if (tid == 0) { m_run_s = -1e30f; l_run_s = 0.f; }
    __syncthreads();

    const f32x4 fz = {0.f, 0.f, 0.f, 0.f};

    for (int tile = 0; tile < Tdim / TT; ++tile) {
        const int t0 = tile * TT;
        // ---- stage hist tile (fp32) ----
        for (int idx = tid; idx < TT * Hdim / 4; idx += NTHR) {
            int r = idx >> 6;
            int kc = (idx & 63) << 2;
            float4 v4 = *(const float4*)&hist[((size_t)b * Tdim + t0 + r) * Hdim + kc];
            *(float4*)&histf[r][kc] = v4;
        }
        if (tid < TT) {
            dtl[tid] = dT[b * Tdim + t0 + tid];
            dll[tid] = dL[b * Tdim + t0 + tid];
        }
        __syncthreads();

        // ---- GEMM1: I = hist @ (Whi1+Wlo1)^T  (2-pass split-bf16) ----
        f32x4 acc[4][2];
        #pragma unroll
        for (int m = 0; m < 4; m++) { acc[m][0] = fz; acc[m][1] = fz; }

        #pragma unroll
        for (int ks = 0; ks < 8; ++ks) {
            const int kb = ks * 32 + g * 8;
            s16x8 afr[4];
            #pragma unroll
            for (int m = 0; m < 4; m++) {
                const float4 x0 = *(const float4*)&histf[m * 16 + c][kb];
                const float4 x1 = *(const float4*)&histf[m * 16 + c][kb + 4];
                uint4 uu = make_uint4(cvt_pk_bf16(x0.x, x0.y), cvt_pk_bf16(x0.z, x0.w),
                                      cvt_pk_bf16(x1.x, x1.y), cvt_pk_bf16(x1.z, x1.w));
                afr[m] = __builtin_bit_cast(s16x8, uu);
            }
            #pragma unroll
            for (int n = 0; n < 2; n++) {
                const int o = ob + n * 16 + c;
                const s16x8 bh = *(const s16x8*)(Whi1 + o * Hdim + kb);
                const s16x8 bl = *(const s16x8*)(Wlo1 + o * Hdim + kb);
                #pragma unroll
                for (int m = 0; m < 4; m++) {
                    acc[m][n] = mfma16(afr[m], bh, acc[m][n]);
                    acc[m][n] = mfma16(afr[m], bl, acc[m][n]);
                }
            }
        }
        // epilogue: add cp + dt*wT + dl*wL (+b_I already in cp), split to hi/lo bf16
        #pragma unroll
        for (int n = 0; n < 2; n++) {
            const int o = ob + n * 16 + c;
            const float base = cpb[o], wt = wTl[o], wl = wLl[o];
            #pragma unroll
            for (int m = 0; m < 4; m++) {
                #pragma unroll
                for (int r = 0; r < 4; r++) {
                    const int row = m * 16 + g * 4 + r;
                    float z = acc[m][n][r] + base + dtl[row] * wt + dll[row] * wl;
                    unsigned short hi = f2bf_rne(z);
                    Ihi[row][o] = hi;
                    Ilo[row][o] = f2bf_rne(z - bf2f(hi));
                }
            }
        }
        __syncthreads();

        // ---- GEMM2: z = (Ihi+Ilo) @ (Whi2+Wlo2)^T  (3-pass, drop lo*lo) ----
        f32x4 acc2[4][2];
        #pragma unroll
        for (int m = 0; m < 4; m++) { acc2[m][0] = fz; acc2[m][1] = fz; }

        #pragma unroll
        for (int ks = 0; ks < 8; ++ks) {
            const int kb = ks * 32 + g * 8;
            s16x8 ah[4], al[4];
            #pragma unroll
            for (int m = 0; m < 4; m++) {
                ah[m] = *(const s16x8*)&Ihi[m * 16 + c][kb];
                al[m] = *(const s16x8*)&Ilo[m * 16 + c][kb];
            }
            #pragma unroll
            for (int n = 0; n < 2; n++) {
                const int o = ob + n * 16 + c;
                const s16x8 bh = *(const s16x8*)(Whi2 + o * Hdim + kb);
                const s16x8 bl = *(const s16x8*)(Wlo2 + o * Hdim + kb);
                #pragma unroll
                for (int m = 0; m < 4; m++) {
                    acc2[m][n] = mfma16(ah[m], bh, acc2[m][n]);
                    acc2[m][n] = mfma16(ah[m], bl, acc2[m][n]);
                    acc2[m][n] = mfma16(al[m], bh, acc2[m][n]);
                }
            }
        }
        // epilogue: tanh, dot with v, reduce 16 lanes -> per-row partial
        #pragma unroll
        for (int m = 0; m < 4; m++) {
            #pragma unroll
            for (int r = 0; r < 4; r++) {
                float s = 0.f;
                #pragma unroll
                for (int n = 0; n < 2; n++) {
                    const int o = ob + n * 16 + c;
                    float z = acc2[m][n][r] + bol[o];
                    s += fast_tanh(z) * vvl[o];
                }
                s += __shfl_xor(s, 1, 64);
                s += __shfl_xor(s, 2, 64);
                s += __shfl_xor(s, 4, 64);
                s += __shfl_xor(s, 8, 64);
                if (c == 0) sc_part[w][m * 16 + g * 4 + r] = s;
            }
        }
        __syncthreads();

        // ---- online softmax update (wave 0) ----
        if (w == 0) {
            float sc = 0.f;
            #pragma unroll
            for (int ww = 0; ww < 8; ww++) sc += sc_part[ww][lane];
            scores_all[t0 + lane] = sc;
            float mt = sc;
            #pragma unroll
            for (int d = 1; d < 64; d <<= 1) mt = fmaxf(mt, __shfl_xor(mt, d, 64));
            const float m_old = m_run_s;
            const float m_new = fmaxf(m_old, mt);
            const float pv = __expf(sc - m_new);
            float ps = pv;
            #pragma unroll
            for (int d = 1; d < 64; d <<= 1) ps += __shfl_xor(ps, d, 64);
            p_t[lane] = pv;
            if (lane == 0) {
                const float fac = __expf(m_old - m_new);
                fac_s = fac;
                l_run_s = l_run_s * fac + ps;
                m_run_s = m_new;
            }
        }
        __syncthreads();

        // ---- weighted accumulation from fp32 staged hist ----
        if (tid < Hdim) {
            const float fac = fac_s;
            float s = s_acc[tid] * fac;
            #pragma unroll 8
            for (int t = 0; t < TT; t++) s += p_t[t] * histf[t][tid];
            s_acc[tid] = s;
        }
        __syncthreads();
    }

    // ---- final outputs: s_t then alpha ----
    if (tid < Hdim) {
        const float inv_l = 1.0f / l_run_s;
        out[b * Hdim + tid] = s_acc[tid] * inv_l;
        out[Bdim * Hdim + b * Tdim + tid] = __expf(scores_all[tid] - m_run_s) * inv_l;
    }
}

extern "C" void kernel_launch(void* const* d_in, const int* in_sizes, int n_in,
                              void* d_out, int out_size, void* d_ws, size_t ws_size,
                              hipStream_t stream) {
    const float* h_tilde = (const float*)d_in[0];
    const float* c_t     = (const float*)d_in[1];
    const float* hist    = (const float*)d_in[2];
    const float* dT      = (const float*)d_in[3];
    const float* dL      = (const float*)d_in[4];
    const float* W_I     = (const float*)d_in[5];
    const float* W_Ih    = (const float*)d_in[6];
    const float* W_I1T   = (const float*)d_in[7];
    const float* W_I1L   = (const float*)d_in[8];
    const float* b_I     = (const float*)d_in[9];
    const float* W_oI    = (const float*)d_in[10];
    const float* b_oI    = (const float*)d_in[11];
    const float* v_t     = (const float*)d_in[12];
    float* out = (float*)d_out;

    char* ws = (char*)d_ws;
    float* cp            = (float*)ws;                               // 512 KB
    unsigned short* Whi1 = (unsigned short*)(ws + 524288);           // 128 KB each
    unsigned short* Wlo1 = (unsigned short*)(ws + 524288 + 131072);
    unsigned short* Whi2 = (unsigned short*)(ws + 524288 + 2 * 131072);
    unsigned short* Wlo2 = (unsigned short*)(ws + 524288 + 3 * 131072);

    prep_weights<<<dim3(256), dim3(256), 0, stream>>>(W_Ih, W_oI, Whi1, Wlo1, Whi2, Wlo2);
    cp_kernel<<<dim3(Bdim), dim3(256), 0, stream>>>(h_tilde, c_t, W_I, b_I, cp);
    attn_main<<<dim3(Bdim), dim3(NTHR), 0, stream>>>(hist, dT, dL, cp,
                                                     Whi1, Wlo1, Whi2, Wlo2,
                                                     W_I1T, W_I1L, b_oI, v_t, out);
}